// Round 1
// baseline (5191.844 us; speedup 1.0000x reference)
//
#include <hip/hip_runtime.h>

#define NN 100000
#define NE 640000
#define DD 128
#define ROUNDS 4

// ---------------------------------------------------------------------------
// out[r][c] = (resid ? resid[r][c] : 0) + relu( sum_k A[r][k]*W[k][c] + b[c] )
// A: (n,128) row-major, W: (128,128) row-major, b: (128)
// Block: 256 threads. Per grid-stride iter the block computes 32 rows.
// Thread (tid&31)*4 -> 4 cols (float4), (tid>>5)*4 -> 4 rows => 4x4 register tile.
// W (64KB) + 32 A-rows (16KB) staged in LDS => 80KB/block, 2 blocks/CU.
// ---------------------------------------------------------------------------
__global__ __launch_bounds__(256) void gemm_relu_128(
    const float* __restrict__ A,
    const float* __restrict__ W,
    const float* __restrict__ bias,
    const float* __restrict__ resid,
    float* __restrict__ out,
    int n)
{
    __shared__ float Ws[DD * DD];
    __shared__ float As[32 * DD];

    for (int i = threadIdx.x * 4; i < DD * DD; i += 256 * 4) {
        *(float4*)&Ws[i] = *(const float4*)&W[i];
    }

    const int colg = (threadIdx.x & 31) * 4;   // 0,4,...,124
    const int rowg = (threadIdx.x >> 5) * 4;   // 0,4,...,28
    const float4 b4 = *(const float4*)&bias[colg];

    for (long long rowBase = (long long)blockIdx.x * 32; rowBase < n;
         rowBase += (long long)gridDim.x * 32) {
        __syncthreads();  // protect As reuse + first-iter Ws visibility ordering
        const float* Ablk = A + rowBase * DD;
        for (int i = threadIdx.x * 4; i < 32 * DD; i += 256 * 4) {
            *(float4*)&As[i] = *(const float4*)&Ablk[i];
        }
        __syncthreads();

        float4 acc0 = b4, acc1 = b4, acc2 = b4, acc3 = b4;
#pragma unroll 8
        for (int k = 0; k < DD; k++) {
            const float4 w = *(float4*)&Ws[k * DD + colg];
            const float a0 = As[(rowg + 0) * DD + k];
            const float a1 = As[(rowg + 1) * DD + k];
            const float a2 = As[(rowg + 2) * DD + k];
            const float a3 = As[(rowg + 3) * DD + k];
            acc0.x = fmaf(a0, w.x, acc0.x); acc0.y = fmaf(a0, w.y, acc0.y);
            acc0.z = fmaf(a0, w.z, acc0.z); acc0.w = fmaf(a0, w.w, acc0.w);
            acc1.x = fmaf(a1, w.x, acc1.x); acc1.y = fmaf(a1, w.y, acc1.y);
            acc1.z = fmaf(a1, w.z, acc1.z); acc1.w = fmaf(a1, w.w, acc1.w);
            acc2.x = fmaf(a2, w.x, acc2.x); acc2.y = fmaf(a2, w.y, acc2.y);
            acc2.z = fmaf(a2, w.z, acc2.z); acc2.w = fmaf(a2, w.w, acc2.w);
            acc3.x = fmaf(a3, w.x, acc3.x); acc3.y = fmaf(a3, w.y, acc3.y);
            acc3.z = fmaf(a3, w.z, acc3.z); acc3.w = fmaf(a3, w.w, acc3.w);
        }

        float4 accs[4] = {acc0, acc1, acc2, acc3};
#pragma unroll
        for (int i = 0; i < 4; i++) {
            const long long r = rowBase + rowg + i;
            float4 v = accs[i];
            v.x = fmaxf(v.x, 0.f);
            v.y = fmaxf(v.y, 0.f);
            v.z = fmaxf(v.z, 0.f);
            v.w = fmaxf(v.w, 0.f);
            if (resid) {
                const float4 rv = *(const float4*)&resid[r * DD + colg];
                v.x += rv.x; v.y += rv.y; v.z += rv.z; v.w += rv.w;
            }
            *(float4*)&out[r * DD + colg] = v;
        }
    }
}

// ---------------------------------------------------------------------------
// agg[dst[e]][:] += msg[src[e]][:]  via fp32 HW atomics. 32 threads/edge,
// float4 per thread (coalesced 512B row gather).
// ---------------------------------------------------------------------------
__global__ __launch_bounds__(256) void scatter_add_k(
    const float* __restrict__ msg,
    const int* __restrict__ src,
    const int* __restrict__ dst,
    float* __restrict__ agg)
{
    const long long t = (long long)blockIdx.x * 256 + threadIdx.x;
    const int e = (int)(t >> 5);
    if (e >= NE) return;
    const int lane = (int)(t & 31);
    const int s = src[e];
    const int d = dst[e];
    const float4 v = *(const float4*)&msg[(long long)s * DD + lane * 4];
    float* dp = &agg[(long long)d * DD + lane * 4];
    unsafeAtomicAdd(dp + 0, v.x);
    unsafeAtomicAdd(dp + 1, v.y);
    unsafeAtomicAdd(dp + 2, v.z);
    unsafeAtomicAdd(dp + 3, v.w);
}

extern "C" void kernel_launch(void* const* d_in, const int* in_sizes, int n_in,
                              void* d_out, int out_size, void* d_ws, size_t ws_size,
                              hipStream_t stream) {
    const float* x  = (const float*)d_in[0];
    const int*   ei = (const int*)d_in[1];
    const float* Wi = (const float*)d_in[2];
    const float* bi = (const float*)d_in[3];
    const float* Wm = (const float*)d_in[4];
    const float* bm = (const float*)d_in[5];
    const float* Wu = (const float*)d_in[6];
    const float* bu = (const float*)d_in[7];

    const int* src = ei;           // edge_index[0] : message source (gather)
    const int* dst = ei + NE;      // edge_index[1] : scatter-add target

    float* state = (float*)d_out;                    // (N,128)
    float* msg   = (float*)d_ws;                     // (N,128)
    float* agg   = msg + (size_t)NN * DD;            // (N,128)

    const int GEMM_GRID = 1024;
    const int SCAT_GRID = (NE * 32) / 256;           // 80000

    // state = relu(x @ Wi + bi)
    gemm_relu_128<<<GEMM_GRID, 256, 0, stream>>>(x, Wi, bi, nullptr, state, NN);

    for (int r = 0; r < ROUNDS; r++) {
        // msg = relu(state @ Wm[r] + bm[r])
        gemm_relu_128<<<GEMM_GRID, 256, 0, stream>>>(
            state, Wm + (size_t)r * DD * DD, bm + (size_t)r * DD, nullptr, msg, NN);
        // agg = segment_sum(msg[src], dst)
        hipMemsetAsync(agg, 0, (size_t)NN * DD * sizeof(float), stream);
        scatter_add_k<<<SCAT_GRID, 256, 0, stream>>>(msg, src, dst, agg);
        // state = state + relu(agg @ Wu[r] + bu[r])
        gemm_relu_128<<<GEMM_GRID, 256, 0, stream>>>(
            agg, Wu + (size_t)r * DD * DD, bu + (size_t)r * DD, state, state, NN);
    }
}

// Round 2
// 1070.460 us; speedup vs baseline: 4.8501x; 4.8501x over previous
//
#include <hip/hip_runtime.h>

#define NN 100000
#define NE 640000
#define DD 128
#define ROUNDS 4
#define CAP 64   // max in-degree bucket capacity; dst ~ Poisson(6.4), P(deg>=64) ~ 0

// ---------------------------------------------------------------------------
// GEMM: out[r][c] = (resid ? resid[r][c] : 0) + relu( A[r][:] @ W[:][c] + b[c] )
// 256 thr/block, 32 rows/iter, 4x4 register tile, W + A-tile in LDS (80 KB).
// ---------------------------------------------------------------------------
__global__ __launch_bounds__(256) void gemm_relu_128(
    const float* __restrict__ A,
    const float* __restrict__ W,
    const float* __restrict__ bias,
    const float* __restrict__ resid,
    float* __restrict__ out,
    int n)
{
    __shared__ float Ws[DD * DD];
    __shared__ float As[32 * DD];

    for (int i = threadIdx.x * 4; i < DD * DD; i += 256 * 4) {
        *(float4*)&Ws[i] = *(const float4*)&W[i];
    }

    const int colg = (threadIdx.x & 31) * 4;
    const int rowg = (threadIdx.x >> 5) * 4;
    const float4 b4 = *(const float4*)&bias[colg];

    for (long long rowBase = (long long)blockIdx.x * 32; rowBase < n;
         rowBase += (long long)gridDim.x * 32) {
        __syncthreads();
        const float* Ablk = A + rowBase * DD;
        for (int i = threadIdx.x * 4; i < 32 * DD; i += 256 * 4) {
            *(float4*)&As[i] = *(const float4*)&Ablk[i];
        }
        __syncthreads();

        float4 acc0 = b4, acc1 = b4, acc2 = b4, acc3 = b4;
#pragma unroll 8
        for (int k = 0; k < DD; k++) {
            const float4 w = *(float4*)&Ws[k * DD + colg];
            const float a0 = As[(rowg + 0) * DD + k];
            const float a1 = As[(rowg + 1) * DD + k];
            const float a2 = As[(rowg + 2) * DD + k];
            const float a3 = As[(rowg + 3) * DD + k];
            acc0.x = fmaf(a0, w.x, acc0.x); acc0.y = fmaf(a0, w.y, acc0.y);
            acc0.z = fmaf(a0, w.z, acc0.z); acc0.w = fmaf(a0, w.w, acc0.w);
            acc1.x = fmaf(a1, w.x, acc1.x); acc1.y = fmaf(a1, w.y, acc1.y);
            acc1.z = fmaf(a1, w.z, acc1.z); acc1.w = fmaf(a1, w.w, acc1.w);
            acc2.x = fmaf(a2, w.x, acc2.x); acc2.y = fmaf(a2, w.y, acc2.y);
            acc2.z = fmaf(a2, w.z, acc2.z); acc2.w = fmaf(a2, w.w, acc2.w);
            acc3.x = fmaf(a3, w.x, acc3.x); acc3.y = fmaf(a3, w.y, acc3.y);
            acc3.z = fmaf(a3, w.z, acc3.z); acc3.w = fmaf(a3, w.w, acc3.w);
        }

        float4 accs[4] = {acc0, acc1, acc2, acc3};
#pragma unroll
        for (int i = 0; i < 4; i++) {
            const long long r = rowBase + rowg + i;
            float4 v = accs[i];
            v.x = fmaxf(v.x, 0.f);
            v.y = fmaxf(v.y, 0.f);
            v.z = fmaxf(v.z, 0.f);
            v.w = fmaxf(v.w, 0.f);
            if (resid) {
                const float4 rv = *(const float4*)&resid[r * DD + colg];
                v.x += rv.x; v.y += rv.y; v.z += rv.z; v.w += rv.w;
            }
            *(float4*)&out[r * DD + colg] = v;
        }
    }
}

// ---------------------------------------------------------------------------
// CSR-bucket build: for each edge, append src to dst's bucket.
// cursor[] must be zeroed beforehand. Int atomics on 100k counters (~6.4 avg
// contention) — cheap, and done once per launch.
// ---------------------------------------------------------------------------
__global__ __launch_bounds__(256) void bucket_build_k(
    const int* __restrict__ src,
    const int* __restrict__ dst,
    int* __restrict__ cursor,
    int* __restrict__ bucket)
{
    for (int e = blockIdx.x * 256 + threadIdx.x; e < NE; e += gridDim.x * 256) {
        const int d = dst[e];
        const int s = src[e];
        const int pos = atomicAdd(&cursor[d], 1);
        if (pos < CAP) bucket[(long long)d * CAP + pos] = s;
    }
}

// ---------------------------------------------------------------------------
// agg[n][:] = sum_{j in bucket[n]} msg[bucket[n][j]][:]
// 32 lanes per node, float4/lane; 2-way unrolled independent accumulators for
// memory-level parallelism. Pure gather + single coalesced row write.
// ---------------------------------------------------------------------------
__global__ __launch_bounds__(256) void aggregate_k(
    const float* __restrict__ msg,
    const int* __restrict__ cursor,
    const int* __restrict__ bucket,
    float* __restrict__ agg)
{
    const long long t = (long long)blockIdx.x * 256 + threadIdx.x;
    const int node = (int)(t >> 5);
    if (node >= NN) return;
    const int lane4 = (int)(t & 31) * 4;

    int cnt = cursor[node];
    if (cnt > CAP) cnt = CAP;
    const int* bk = bucket + (long long)node * CAP;

    float4 acc0 = {0.f, 0.f, 0.f, 0.f};
    float4 acc1 = {0.f, 0.f, 0.f, 0.f};
    int j = 0;
    for (; j + 1 < cnt; j += 2) {
        const int s0 = bk[j];
        const int s1 = bk[j + 1];
        const float4 a = *(const float4*)&msg[(long long)s0 * DD + lane4];
        const float4 b = *(const float4*)&msg[(long long)s1 * DD + lane4];
        acc0.x += a.x; acc0.y += a.y; acc0.z += a.z; acc0.w += a.w;
        acc1.x += b.x; acc1.y += b.y; acc1.z += b.z; acc1.w += b.w;
    }
    if (j < cnt) {
        const int s0 = bk[j];
        const float4 a = *(const float4*)&msg[(long long)s0 * DD + lane4];
        acc0.x += a.x; acc0.y += a.y; acc0.z += a.z; acc0.w += a.w;
    }
    acc0.x += acc1.x; acc0.y += acc1.y; acc0.z += acc1.z; acc0.w += acc1.w;
    *(float4*)&agg[(long long)node * DD + lane4] = acc0;
}

// Fallback (ws too small): original atomic scatter.
__global__ __launch_bounds__(256) void scatter_add_k(
    const float* __restrict__ msg,
    const int* __restrict__ src,
    const int* __restrict__ dst,
    float* __restrict__ agg)
{
    const long long t = (long long)blockIdx.x * 256 + threadIdx.x;
    const int e = (int)(t >> 5);
    if (e >= NE) return;
    const int lane = (int)(t & 31);
    const int s = src[e];
    const int d = dst[e];
    const float4 v = *(const float4*)&msg[(long long)s * DD + lane * 4];
    float* dp = &agg[(long long)d * DD + lane * 4];
    unsafeAtomicAdd(dp + 0, v.x);
    unsafeAtomicAdd(dp + 1, v.y);
    unsafeAtomicAdd(dp + 2, v.z);
    unsafeAtomicAdd(dp + 3, v.w);
}

extern "C" void kernel_launch(void* const* d_in, const int* in_sizes, int n_in,
                              void* d_out, int out_size, void* d_ws, size_t ws_size,
                              hipStream_t stream) {
    const float* x  = (const float*)d_in[0];
    const int*   ei = (const int*)d_in[1];
    const float* Wi = (const float*)d_in[2];
    const float* bi = (const float*)d_in[3];
    const float* Wm = (const float*)d_in[4];
    const float* bm = (const float*)d_in[5];
    const float* Wu = (const float*)d_in[6];
    const float* bu = (const float*)d_in[7];

    const int* src = ei;           // edge_index[0] : gather source
    const int* dst = ei + NE;      // edge_index[1] : aggregation target

    float* state = (float*)d_out;                    // (N,128)
    float* msg   = (float*)d_ws;                     // (N,128)  51.2 MB
    float* agg   = msg + (size_t)NN * DD;            // (N,128)  51.2 MB
    int*   cursor = (int*)(agg + (size_t)NN * DD);   // (N)      0.4 MB
    int*   bucket = cursor + NN;                     // (N,CAP)  25.6 MB

    const size_t needed = (size_t)NN * DD * 8 + (size_t)NN * 4 + (size_t)NN * CAP * 4;
    const bool use_bucket = ws_size >= needed;

    const int GEMM_GRID = 1024;
    const int NODE_GRID = (NN * 32 + 255) / 256;     // 12500
    const int SCAT_GRID = (NE * 32) / 256;           // 80000 (fallback)

    if (use_bucket) {
        // Build per-destination buckets once (same work every call).
        hipMemsetAsync(cursor, 0, (size_t)NN * 4, stream);
        bucket_build_k<<<1024, 256, 0, stream>>>(src, dst, cursor, bucket);
    }

    // state = relu(x @ Wi + bi)
    gemm_relu_128<<<GEMM_GRID, 256, 0, stream>>>(x, Wi, bi, nullptr, state, NN);

    for (int r = 0; r < ROUNDS; r++) {
        // msg = relu(state @ Wm[r] + bm[r])
        gemm_relu_128<<<GEMM_GRID, 256, 0, stream>>>(
            state, Wm + (size_t)r * DD * DD, bm + (size_t)r * DD, nullptr, msg, NN);
        // agg = segment_sum(msg[src], dst)
        if (use_bucket) {
            aggregate_k<<<NODE_GRID, 256, 0, stream>>>(msg, cursor, bucket, agg);
        } else {
            hipMemsetAsync(agg, 0, (size_t)NN * DD * sizeof(float), stream);
            scatter_add_k<<<SCAT_GRID, 256, 0, stream>>>(msg, src, dst, agg);
        }
        // state = state + relu(agg @ Wu[r] + bu[r])
        gemm_relu_128<<<GEMM_GRID, 256, 0, stream>>>(
            agg, Wu + (size_t)r * DD * DD, bu + (size_t)r * DD, state, state, NN);
    }
}

// Round 3
// 655.521 us; speedup vs baseline: 7.9202x; 1.6330x over previous
//
#include <hip/hip_runtime.h>

#define NN 100000
#define NE 640000
#define DD 128
#define ROUNDS 4
#define CAP 64   // max in-degree bucket capacity; dst ~ Poisson(6.4), P(deg>=64) ~ 0

typedef float f32x4 __attribute__((ext_vector_type(4)));
typedef short short8 __attribute__((ext_vector_type(8)));

__device__ inline ushort f2bf(float f) {
    union { float f; uint u; } v; v.f = f;
    uint u = v.u + 0x7fff + ((v.u >> 16) & 1);   // RNE; inputs finite
    return (ushort)(u >> 16);
}
__device__ inline float bf2f(ushort h) {
    union { uint u; float f; } v; v.u = ((uint)h) << 16;
    return v.f;
}

// ---------------------------------------------------------------------------
// C = resid + relu(A @ W + b) via bf16x3-split MFMA (fp32-class accuracy).
// A (n,128) fp32 row-major, W (128,128) fp32 row-major.
// Block=256 (4 waves), 32-row tile; wave (w&1)->rows 16*(w&1), (w>>1)->cols 64*(w>>1).
// W hi/lo fragments live in registers (loaded from global once per block).
// A tile staged in LDS as bf16 hi/lo, row pad +8 el (2-way bank alias = free).
// ---------------------------------------------------------------------------
#define TM 32
#define KPAD 136   // 128 + 8 pad (272 B row stride, 16B aligned)

__global__ __launch_bounds__(256, 2) void gemm_mfma_128(
    const float* __restrict__ A,
    const float* __restrict__ W,
    const float* __restrict__ bias,
    const float* __restrict__ resid,
    float* __restrict__ out,
    int n)
{
    __shared__ ushort AsH[TM * KPAD];
    __shared__ ushort AsL[TM * KPAD];

    const int tid  = threadIdx.x;
    const int wave = tid >> 6;
    const int lane = tid & 63;
    const int ln   = lane & 15;
    const int q    = lane >> 4;
    const int m16  = (wave & 1) * 16;       // row offset inside tile
    const int nB   = (wave >> 1) * 64;      // col offset

    // ---- W fragments (hi/lo) from global, once per block ----
    // B-frag layout: lane holds B[k = s*32 + q*8 + j][n = nB + b*16 + ln], j=0..7
    short8 WfH[4][4], WfL[4][4];            // [kstep][nblk] : 128 VGPRs
#pragma unroll
    for (int s = 0; s < 4; s++) {
#pragma unroll
        for (int b = 0; b < 4; b++) {
            const float* wp = W + (size_t)(s * 32 + q * 8) * DD + nB + b * 16 + ln;
            short8 h, l;
#pragma unroll
            for (int j = 0; j < 8; j++) {
                const float f = wp[(size_t)j * DD];
                const ushort hh = f2bf(f);
                h[j] = (short)hh;
                l[j] = (short)f2bf(f - bf2f(hh));
            }
            WfH[s][b] = h; WfL[s][b] = l;
        }
    }

    float biasv[4];
#pragma unroll
    for (int b = 0; b < 4; b++) biasv[b] = bias[nB + b * 16 + ln];

    // staging mapping: thread -> row tid>>3, k-segment (tid&7)*16
    const int srow = tid >> 3;
    const int sk   = (tid & 7) * 16;

    for (int rowBase = blockIdx.x * TM; rowBase < n; rowBase += gridDim.x * TM) {
        __syncthreads();
        {
            const float* ap = A + (size_t)(rowBase + srow) * DD + sk;
            uint hw[8], lw[8];
#pragma unroll
            for (int j = 0; j < 4; j++) {
                const float4 f = ((const float4*)ap)[j];
                const ushort h0 = f2bf(f.x), h1 = f2bf(f.y), h2 = f2bf(f.z), h3 = f2bf(f.w);
                hw[2 * j]     = (uint)h0 | ((uint)h1 << 16);
                hw[2 * j + 1] = (uint)h2 | ((uint)h3 << 16);
                const ushort l0 = f2bf(f.x - bf2f(h0)), l1 = f2bf(f.y - bf2f(h1));
                const ushort l2 = f2bf(f.z - bf2f(h2)), l3 = f2bf(f.w - bf2f(h3));
                lw[2 * j]     = (uint)l0 | ((uint)l1 << 16);
                lw[2 * j + 1] = (uint)l2 | ((uint)l3 << 16);
            }
            *(uint4*)&AsH[srow * KPAD + sk]     = make_uint4(hw[0], hw[1], hw[2], hw[3]);
            *(uint4*)&AsH[srow * KPAD + sk + 8] = make_uint4(hw[4], hw[5], hw[6], hw[7]);
            *(uint4*)&AsL[srow * KPAD + sk]     = make_uint4(lw[0], lw[1], lw[2], lw[3]);
            *(uint4*)&AsL[srow * KPAD + sk + 8] = make_uint4(lw[4], lw[5], lw[6], lw[7]);
        }
        __syncthreads();

        f32x4 acc[4];
#pragma unroll
        for (int b = 0; b < 4; b++) acc[b] = (f32x4){biasv[b], biasv[b], biasv[b], biasv[b]};

#pragma unroll
        for (int s = 0; s < 4; s++) {
            // A-frag: lane holds A[m = m16 + ln][k = s*32 + q*8 + j]
            const short8 aH = *(const short8*)&AsH[(m16 + ln) * KPAD + s * 32 + q * 8];
            const short8 aL = *(const short8*)&AsL[(m16 + ln) * KPAD + s * 32 + q * 8];
#pragma unroll
            for (int b = 0; b < 4; b++) {
                acc[b] = __builtin_amdgcn_mfma_f32_16x16x32_bf16(aH, WfH[s][b], acc[b], 0, 0, 0);
                acc[b] = __builtin_amdgcn_mfma_f32_16x16x32_bf16(aH, WfL[s][b], acc[b], 0, 0, 0);
                acc[b] = __builtin_amdgcn_mfma_f32_16x16x32_bf16(aL, WfH[s][b], acc[b], 0, 0, 0);
            }
        }

        // epilogue: C/D layout col = ln, row = q*4 + r
#pragma unroll
        for (int b = 0; b < 4; b++) {
            const int col = nB + b * 16 + ln;
#pragma unroll
            for (int r = 0; r < 4; r++) {
                const size_t row = (size_t)rowBase + m16 + q * 4 + r;
                float v = fmaxf(acc[b][r], 0.f);
                if (resid) v += resid[row * DD + col];
                out[row * DD + col] = v;
            }
        }
    }
}

// ---------------------------------------------------------------------------
// CSR-bucket build: append src to dst's bucket. cursor[] zeroed beforehand.
// ---------------------------------------------------------------------------
__global__ __launch_bounds__(256) void bucket_build_k(
    const int* __restrict__ src,
    const int* __restrict__ dst,
    int* __restrict__ cursor,
    int* __restrict__ bucket)
{
    for (int e = blockIdx.x * 256 + threadIdx.x; e < NE; e += gridDim.x * 256) {
        const int d = dst[e];
        const int s = src[e];
        const int pos = atomicAdd(&cursor[d], 1);
        if (pos < CAP) bucket[(long long)d * CAP + pos] = s;
    }
}

// ---------------------------------------------------------------------------
// agg[n][:] = sum_{j in bucket[n]} msg[bucket[n][j]][:]
// ---------------------------------------------------------------------------
__global__ __launch_bounds__(256) void aggregate_k(
    const float* __restrict__ msg,
    const int* __restrict__ cursor,
    const int* __restrict__ bucket,
    float* __restrict__ agg)
{
    const long long t = (long long)blockIdx.x * 256 + threadIdx.x;
    const int node = (int)(t >> 5);
    if (node >= NN) return;
    const int lane4 = (int)(t & 31) * 4;

    int cnt = cursor[node];
    if (cnt > CAP) cnt = CAP;
    const int* bk = bucket + (long long)node * CAP;

    float4 acc0 = {0.f, 0.f, 0.f, 0.f};
    float4 acc1 = {0.f, 0.f, 0.f, 0.f};
    int j = 0;
    for (; j + 1 < cnt; j += 2) {
        const int s0 = bk[j];
        const int s1 = bk[j + 1];
        const float4 a = *(const float4*)&msg[(long long)s0 * DD + lane4];
        const float4 b = *(const float4*)&msg[(long long)s1 * DD + lane4];
        acc0.x += a.x; acc0.y += a.y; acc0.z += a.z; acc0.w += a.w;
        acc1.x += b.x; acc1.y += b.y; acc1.z += b.z; acc1.w += b.w;
    }
    if (j < cnt) {
        const int s0 = bk[j];
        const float4 a = *(const float4*)&msg[(long long)s0 * DD + lane4];
        acc0.x += a.x; acc0.y += a.y; acc0.z += a.z; acc0.w += a.w;
    }
    acc0.x += acc1.x; acc0.y += acc1.y; acc0.z += acc1.z; acc0.w += acc1.w;
    *(float4*)&agg[(long long)node * DD + lane4] = acc0;
}

// Fallback (ws too small): atomic scatter.
__global__ __launch_bounds__(256) void scatter_add_k(
    const float* __restrict__ msg,
    const int* __restrict__ src,
    const int* __restrict__ dst,
    float* __restrict__ agg)
{
    const long long t = (long long)blockIdx.x * 256 + threadIdx.x;
    const int e = (int)(t >> 5);
    if (e >= NE) return;
    const int lane = (int)(t & 31);
    const int s = src[e];
    const int d = dst[e];
    const float4 v = *(const float4*)&msg[(long long)s * DD + lane * 4];
    float* dp = &agg[(long long)d * DD + lane * 4];
    unsafeAtomicAdd(dp + 0, v.x);
    unsafeAtomicAdd(dp + 1, v.y);
    unsafeAtomicAdd(dp + 2, v.z);
    unsafeAtomicAdd(dp + 3, v.w);
}

extern "C" void kernel_launch(void* const* d_in, const int* in_sizes, int n_in,
                              void* d_out, int out_size, void* d_ws, size_t ws_size,
                              hipStream_t stream) {
    const float* x  = (const float*)d_in[0];
    const int*   ei = (const int*)d_in[1];
    const float* Wi = (const float*)d_in[2];
    const float* bi = (const float*)d_in[3];
    const float* Wm = (const float*)d_in[4];
    const float* bm = (const float*)d_in[5];
    const float* Wu = (const float*)d_in[6];
    const float* bu = (const float*)d_in[7];

    const int* src = ei;           // edge_index[0] : gather source
    const int* dst = ei + NE;      // edge_index[1] : aggregation target

    float* state = (float*)d_out;                    // (N,128)
    float* msg   = (float*)d_ws;                     // (N,128)  51.2 MB
    float* agg   = msg + (size_t)NN * DD;            // (N,128)  51.2 MB
    int*   cursor = (int*)(agg + (size_t)NN * DD);   // (N)      0.4 MB
    int*   bucket = cursor + NN;                     // (N,CAP)  25.6 MB

    const size_t needed = (size_t)NN * DD * 8 + (size_t)NN * 4 + (size_t)NN * CAP * 4;
    const bool use_bucket = ws_size >= needed;

    const int GEMM_GRID = 512;                       // 2 blocks/CU, ~6 tiles each
    const int NODE_GRID = (NN * 32 + 255) / 256;     // 12500
    const int SCAT_GRID = (NE * 32) / 256;           // 80000 (fallback)

    if (use_bucket) {
        hipMemsetAsync(cursor, 0, (size_t)NN * 4, stream);
        bucket_build_k<<<1024, 256, 0, stream>>>(src, dst, cursor, bucket);
    }

    // state = relu(x @ Wi + bi)
    gemm_mfma_128<<<GEMM_GRID, 256, 0, stream>>>(x, Wi, bi, nullptr, state, NN);

    for (int r = 0; r < ROUNDS; r++) {
        // msg = relu(state @ Wm[r] + bm[r])
        gemm_mfma_128<<<GEMM_GRID, 256, 0, stream>>>(
            state, Wm + (size_t)r * DD * DD, bm + (size_t)r * DD, nullptr, msg, NN);
        // agg = segment_sum(msg[src], dst)
        if (use_bucket) {
            aggregate_k<<<NODE_GRID, 256, 0, stream>>>(msg, cursor, bucket, agg);
        } else {
            hipMemsetAsync(agg, 0, (size_t)NN * DD * sizeof(float), stream);
            scatter_add_k<<<SCAT_GRID, 256, 0, stream>>>(msg, src, dst, agg);
        }
        // state = state + relu(agg @ Wu[r] + bu[r])
        gemm_mfma_128<<<GEMM_GRID, 256, 0, stream>>>(
            agg, Wu + (size_t)r * DD * DD, bu + (size_t)r * DD, state, state, NN);
    }
}

// Round 4
// 612.078 us; speedup vs baseline: 8.4823x; 1.0710x over previous
//
#include <hip/hip_runtime.h>

#define NN 100000
#define NE 640000
#define DD 128
#define ROUNDS 4
#define CAP 48          // max in-degree; Poisson(6.4) => P(deg>=48) ~ 1e-30
#define NTILE 6250      // NN / 16
#define NTASK 12500     // NTILE * 2 col-halves

typedef float f32x4 __attribute__((ext_vector_type(4)));
typedef _Float16 half8 __attribute__((ext_vector_type(8)));

// ---------------------------------------------------------------------------
// Weight prep: W (128x128 fp32 row-major [k][n]) -> WT hi/lo fp16 [n][k].
// 9 matrices: 0=Wi, 1..4=Wm[r], 5..8=Wu[r]. One block per (mat, k-row).
// ---------------------------------------------------------------------------
__global__ __launch_bounds__(128) void wprep_k(
    const float* __restrict__ Wi, const float* __restrict__ Wm,
    const float* __restrict__ Wu,
    _Float16* __restrict__ WTh, _Float16* __restrict__ WTl)
{
    const int mat = blockIdx.x >> 7;
    const int k   = blockIdx.x & 127;
    const int n   = threadIdx.x;
    const float* W = (mat == 0) ? Wi
                   : (mat <= 4) ? Wm + (size_t)(mat - 1) * DD * DD
                                : Wu + (size_t)(mat - 5) * DD * DD;
    const float f = W[(size_t)k * DD + n];
    const _Float16 h = (_Float16)f;
    WTh[(size_t)mat * DD * DD + (size_t)n * DD + k] = h;
    WTl[(size_t)mat * DD * DD + (size_t)n * DD + k] = (_Float16)(f - (float)h);
}

// ---------------------------------------------------------------------------
// x (fp32) -> Xh/Xl fp16 split. 8 elements per thread.
// ---------------------------------------------------------------------------
__global__ __launch_bounds__(256) void xsplit_k(
    const float* __restrict__ x, _Float16* __restrict__ Xh, _Float16* __restrict__ Xl)
{
    const size_t i = ((size_t)blockIdx.x * 256 + threadIdx.x) * 8;
    if (i >= (size_t)NN * DD) return;
    half8 h, l;
#pragma unroll
    for (int j = 0; j < 8; j++) {
        const float f = x[i + j];
        const _Float16 hh = (_Float16)f;
        h[j] = hh;
        l[j] = (_Float16)(f - (float)hh);
    }
    *(half8*)&Xh[i] = h;
    *(half8*)&Xl[i] = l;
}

// ---------------------------------------------------------------------------
// LDS-free W-stationary GEMM, fp16 MFMA (16x16x32), split-accuracy:
//   O = [resid +] relu( (Ah[+Al]) @ (Wh+Wl) + b )
// Each wave: one 16-row x 64-col task; W hi/lo fragments in 128 VGPRs
// (loaded once per wave from pre-transposed WT[n][k]); A-fragments loaded
// directly from global (16B per lane, 100% line utilization). No LDS, no
// __syncthreads — waves fully independent, 6.1 tasks each (grid 512x256).
// Terms: Ah*Wh + Ah*Wl (+ Al*Wh if Al) — fp32-class product accuracy.
// Outputs: Oh (fp16 hi), Ol (optional fp16 lo), Of (optional fp32).
// ---------------------------------------------------------------------------
__global__ __launch_bounds__(256, 2) void gemm16(
    const _Float16* __restrict__ Ah, const _Float16* __restrict__ Al,
    const _Float16* __restrict__ WTh, const _Float16* __restrict__ WTl,
    const float* __restrict__ bias,
    const _Float16* __restrict__ Rh, const _Float16* __restrict__ Rl,
    _Float16* __restrict__ Oh, _Float16* __restrict__ Ol,
    float* __restrict__ Of)
{
    const int lane = threadIdx.x & 63;
    const int ln   = lane & 15;
    const int q    = lane >> 4;
    const int wave0 = ((int)blockIdx.x * 256 + (int)threadIdx.x) >> 6;
    const int nWaves = ((int)gridDim.x * 256) >> 6;

    // B-frag: lane holds B[k = s*32 + q*8 + j][n = colBase + b*16 + ln], j=0..7
    // colBase resolved per task (two col-halves per tile) -> preload both? No:
    // col-half is (task & 1); tasks for a given wave alternate parity only if
    // nWaves is odd — it isn't (2048). So parity is FIXED per wave: preload once.
    // task = wave0 + i*nWaves  ->  (task & 1) == (wave0 & 1) since nWaves even.
    const int colBase = (wave0 & 1) * 64;

    half8 WH[4][4], WL[4][4];
#pragma unroll
    for (int s = 0; s < 4; s++) {
#pragma unroll
        for (int b = 0; b < 4; b++) {
            const size_t off = (size_t)(colBase + b * 16 + ln) * DD + s * 32 + q * 8;
            WH[s][b] = *(const half8*)&WTh[off];
            WL[s][b] = *(const half8*)&WTl[off];
        }
    }

    float biasv[4];
#pragma unroll
    for (int b = 0; b < 4; b++) biasv[b] = bias[colBase + b * 16 + ln];

    for (int task = wave0; task < NTASK; task += nWaves) {
        const int tile = task >> 1;
        const size_t rowA = (size_t)tile * 16 + ln;     // A-frag row (m = ln)

        half8 aH[4], aL[4];
#pragma unroll
        for (int s = 0; s < 4; s++)
            aH[s] = *(const half8*)&Ah[rowA * DD + s * 32 + q * 8];
        if (Al) {
#pragma unroll
            for (int s = 0; s < 4; s++)
                aL[s] = *(const half8*)&Al[rowA * DD + s * 32 + q * 8];
        }

        f32x4 acc[4];
#pragma unroll
        for (int b = 0; b < 4; b++)
            acc[b] = (f32x4){biasv[b], biasv[b], biasv[b], biasv[b]};

#pragma unroll
        for (int s = 0; s < 4; s++) {
#pragma unroll
            for (int b = 0; b < 4; b++) {
                acc[b] = __builtin_amdgcn_mfma_f32_16x16x32_f16(aH[s], WH[s][b], acc[b], 0, 0, 0);
                acc[b] = __builtin_amdgcn_mfma_f32_16x16x32_f16(aH[s], WL[s][b], acc[b], 0, 0, 0);
            }
            if (Al) {
#pragma unroll
                for (int b = 0; b < 4; b++)
                    acc[b] = __builtin_amdgcn_mfma_f32_16x16x32_f16(aL[s], WH[s][b], acc[b], 0, 0, 0);
            }
        }

        // C/D layout: col = ln, row = q*4 + r
#pragma unroll
        for (int b = 0; b < 4; b++) {
            const int col = colBase + b * 16 + ln;
#pragma unroll
            for (int r = 0; r < 4; r++) {
                const size_t row = (size_t)tile * 16 + q * 4 + r;
                float v = fmaxf(acc[b][r], 0.f);
                if (Rh) v += (float)Rh[row * DD + col] + (float)Rl[row * DD + col];
                const _Float16 h = (_Float16)v;
                Oh[row * DD + col] = h;
                if (Ol) Ol[row * DD + col] = (_Float16)(v - (float)h);
                if (Of) Of[row * DD + col] = v;
            }
        }
    }
}

// ---------------------------------------------------------------------------
// CSR-bucket build: append src to dst's bucket. cursor[] zeroed beforehand.
// ---------------------------------------------------------------------------
__global__ __launch_bounds__(256) void bucket_build_k(
    const int* __restrict__ src,
    const int* __restrict__ dst,
    int* __restrict__ cursor,
    int* __restrict__ bucket)
{
    for (int e = blockIdx.x * 256 + threadIdx.x; e < NE; e += gridDim.x * 256) {
        const int d = dst[e];
        const int s = src[e];
        const int pos = atomicAdd(&cursor[d], 1);
        if (pos < CAP) bucket[(long long)d * CAP + pos] = s;
    }
}

// ---------------------------------------------------------------------------
// agg[n][:] = sum msg[bucket[n][j]][:]  (fp16 gather, fp32 accumulate,
// fp16 store). 16 lanes/node, half8 (16B) per lane -> 256B/row coalesced.
// ---------------------------------------------------------------------------
__global__ __launch_bounds__(256) void aggregate16(
    const _Float16* __restrict__ msg,
    const int* __restrict__ cursor,
    const int* __restrict__ bucket,
    _Float16* __restrict__ agg)
{
    const long long t = (long long)blockIdx.x * 256 + threadIdx.x;
    const int node = (int)(t >> 4);
    if (node >= NN) return;
    const int c8 = (int)(t & 15) * 8;

    int cnt = cursor[node];
    if (cnt > CAP) cnt = CAP;
    const int* bk = bucket + (long long)node * CAP;

    float a0[8] = {0, 0, 0, 0, 0, 0, 0, 0};
    float a1[8] = {0, 0, 0, 0, 0, 0, 0, 0};
    int j = 0;
    for (; j + 1 < cnt; j += 2) {
        const half8 v0 = *(const half8*)&msg[(size_t)bk[j] * DD + c8];
        const half8 v1 = *(const half8*)&msg[(size_t)bk[j + 1] * DD + c8];
#pragma unroll
        for (int i = 0; i < 8; i++) { a0[i] += (float)v0[i]; a1[i] += (float)v1[i]; }
    }
    if (j < cnt) {
        const half8 v0 = *(const half8*)&msg[(size_t)bk[j] * DD + c8];
#pragma unroll
        for (int i = 0; i < 8; i++) a0[i] += (float)v0[i];
    }
    half8 o;
#pragma unroll
    for (int i = 0; i < 8; i++) o[i] = (_Float16)(a0[i] + a1[i]);
    *(half8*)&agg[(size_t)node * DD + c8] = o;
}

extern "C" void kernel_launch(void* const* d_in, const int* in_sizes, int n_in,
                              void* d_out, int out_size, void* d_ws, size_t ws_size,
                              hipStream_t stream) {
    const float* x  = (const float*)d_in[0];
    const int*   ei = (const int*)d_in[1];
    const float* Wi = (const float*)d_in[2];
    const float* bi = (const float*)d_in[3];
    const float* Wm = (const float*)d_in[4];
    const float* bm = (const float*)d_in[5];
    const float* Wu = (const float*)d_in[6];
    const float* bu = (const float*)d_in[7];

    const int* src = ei;           // edge_index[0] : gather source
    const int* dst = ei + NE;      // edge_index[1] : aggregation target

    // Workspace carve (122.6 MB; R2/R3 proved ws_size >= 128.4 MB):
    const size_t NELE = (size_t)NN * DD;                 // 12.8M
    _Float16* msg = (_Float16*)d_ws;                     // 25.6 MB  [alias Xh]
    _Float16* agg = msg + NELE;                          // 25.6 MB  [alias Xl]
    _Float16* Sh  = agg + NELE;                          // 25.6 MB  state hi
    _Float16* Sl  = Sh + NELE;                           // 25.6 MB  state lo
    _Float16* WTh = Sl + NELE;                           // 9*32 KB
    _Float16* WTl = WTh + 9 * DD * DD;                   // 9*32 KB
    int* cursor = (int*)(WTl + 9 * DD * DD);             // 0.4 MB
    int* bucket = cursor + NN;                           // 19.2 MB

    // ---- one-time prep (per launch) ----
    hipMemsetAsync(cursor, 0, (size_t)NN * 4, stream);
    bucket_build_k<<<1024, 256, 0, stream>>>(src, dst, cursor, bucket);
    wprep_k<<<9 * 128, 128, 0, stream>>>(Wi, Wm, Wu, WTh, WTl);
    xsplit_k<<<NTILE, 256, 0, stream>>>(x, msg /*Xh*/, agg /*Xl*/);

    const int GG = 512;     // 2048 waves (even per-wave col-parity), ~6 tasks/wave
    const int AG = NTILE;   // 6250 blocks, 16 lanes/node

    // state = relu(x @ Wi + bi)   (3-term, no resid, write hi+lo)
    gemm16<<<GG, 256, 0, stream>>>(msg, agg, WTh, WTl, bi,
                                   nullptr, nullptr, Sh, Sl, nullptr);

    for (int r = 0; r < ROUNDS; r++) {
        const _Float16* WmTh = WTh + (size_t)(1 + r) * DD * DD;
        const _Float16* WmTl = WTl + (size_t)(1 + r) * DD * DD;
        const _Float16* WuTh = WTh + (size_t)(5 + r) * DD * DD;
        const _Float16* WuTl = WTl + (size_t)(5 + r) * DD * DD;

        // msg = relu(state @ Wm[r] + bm[r])   (3-term, single fp16 out)
        gemm16<<<GG, 256, 0, stream>>>(Sh, Sl, WmTh, WmTl, bm + (size_t)r * DD,
                                       nullptr, nullptr, msg, nullptr, nullptr);
        // agg = segment_sum(msg[src], dst)
        aggregate16<<<AG, 256, 0, stream>>>(msg, cursor, bucket, agg);
        // state += relu(agg @ Wu[r] + bu[r])  (2-term, resid, in-place hi/lo;
        // final round also writes fp32 d_out)
        gemm16<<<GG, 256, 0, stream>>>(agg, nullptr, WuTh, WuTl, bu + (size_t)r * DD,
                                       Sh, Sl, Sh, Sl,
                                       (r == ROUNDS - 1) ? (float*)d_out : nullptr);
    }
}

// Round 5
// 552.905 us; speedup vs baseline: 9.3901x; 1.1070x over previous
//
#include <hip/hip_runtime.h>

#define NN 100000
#define NE 640000
#define DD 128
#define ROUNDS 4
#define NTILE 6250      // NN / 16
#define NTASK 12500     // NTILE * 2 col-halves
#define NB 391          // ceil(NN / 256)

typedef float f32x4 __attribute__((ext_vector_type(4)));
typedef _Float16 half8 __attribute__((ext_vector_type(8)));

// ---------------------------------------------------------------------------
// CSR build, exact offsets (bucket array small enough to live in L2):
//   hist -> per-block sums -> block-offset scan -> per-element offsets -> scatter
// ---------------------------------------------------------------------------
__global__ __launch_bounds__(256) void hist_k(
    const int* __restrict__ dst, int* __restrict__ cnt)
{
    for (int e = blockIdx.x * 256 + threadIdx.x; e < NE; e += gridDim.x * 256)
        atomicAdd(&cnt[dst[e]], 1);
}

__global__ __launch_bounds__(256) void bsum_k(
    const int* __restrict__ cnt, int* __restrict__ bsum)
{
    __shared__ int s[256];
    const int i = blockIdx.x * 256 + threadIdx.x;
    s[threadIdx.x] = (i < NN) ? cnt[i] : 0;
    __syncthreads();
    for (int d = 128; d > 0; d >>= 1) {
        if (threadIdx.x < d) s[threadIdx.x] += s[threadIdx.x + d];
        __syncthreads();
    }
    if (threadIdx.x == 0) bsum[blockIdx.x] = s[0];
}

__global__ __launch_bounds__(512) void bscan_k(
    const int* __restrict__ bsum, int* __restrict__ boff)
{
    __shared__ int s[NB];
    if (threadIdx.x < NB) s[threadIdx.x] = bsum[threadIdx.x];
    __syncthreads();
    if (threadIdx.x == 0) {
        int acc = 0;
        for (int i = 0; i < NB; i++) { const int v = s[i]; s[i] = acc; acc += v; }
    }
    __syncthreads();
    if (threadIdx.x < NB) boff[threadIdx.x] = s[threadIdx.x];
}

__global__ __launch_bounds__(256) void offs_k(
    const int* __restrict__ cnt, const int* __restrict__ boff,
    int* __restrict__ offs)
{
    __shared__ int s[256];
    const int i = blockIdx.x * 256 + threadIdx.x;
    const int v = (i < NN) ? cnt[i] : 0;
    s[threadIdx.x] = v;
    __syncthreads();
    for (int d = 1; d < 256; d <<= 1) {
        const int t = (threadIdx.x >= d) ? s[threadIdx.x - d] : 0;
        __syncthreads();
        s[threadIdx.x] += t;
        __syncthreads();
    }
    if (i < NN) offs[i] = boff[blockIdx.x] + s[threadIdx.x] - v;  // exclusive
}

__global__ __launch_bounds__(256) void scatter_k(
    const int* __restrict__ src, const int* __restrict__ dst,
    const int* __restrict__ offs, int* __restrict__ run,
    int* __restrict__ csr)
{
    for (int e = blockIdx.x * 256 + threadIdx.x; e < NE; e += gridDim.x * 256) {
        const int d = dst[e];
        const int p = offs[d] + atomicAdd(&run[d], 1);
        csr[p] = src[e];
    }
}

// ---------------------------------------------------------------------------
// Weight prep: W (128x128 fp32 [k][n]) -> WT hi/lo fp16 [n][k], 9 matrices.
// ---------------------------------------------------------------------------
__global__ __launch_bounds__(128) void wprep_k(
    const float* __restrict__ Wi, const float* __restrict__ Wm,
    const float* __restrict__ Wu,
    _Float16* __restrict__ WTh, _Float16* __restrict__ WTl)
{
    const int mat = blockIdx.x >> 7;
    const int k   = blockIdx.x & 127;
    const int n   = threadIdx.x;
    const float* W = (mat == 0) ? Wi
                   : (mat <= 4) ? Wm + (size_t)(mat - 1) * DD * DD
                                : Wu + (size_t)(mat - 5) * DD * DD;
    const float f = W[(size_t)k * DD + n];
    const _Float16 h = (_Float16)f;
    WTh[(size_t)mat * DD * DD + (size_t)n * DD + k] = h;
    WTl[(size_t)mat * DD * DD + (size_t)n * DD + k] = (_Float16)(f - (float)h);
}

// ---------------------------------------------------------------------------
// LDS-free W-stationary GEMM, fp16 MFMA 16x16x32, software-pipelined tasks:
//   O = [resid +] relu( A @ (Wh+Wl) + b )
// Wave-private: one 16-row x 64-col task/iter; W hi/lo frags in 128 VGPRs.
// A from fp16 (Ah) or fp32 (Af32, converted in-reg — input gemm only).
// Next task's A-fragments are loaded BEFORE current task's MFMAs (prefetch),
// so the ~500-cyc global load latency hides behind MFMA + epilogue.
// ---------------------------------------------------------------------------
__device__ __forceinline__ void loadA(
    const _Float16* __restrict__ Ah, const float* __restrict__ Af32,
    size_t rowA, int q, half8 a[4])
{
    if (Af32) {
        const float* p = Af32 + rowA * DD + q * 8;
#pragma unroll
        for (int s = 0; s < 4; s++) {
            const float4 f0 = *(const float4*)&p[s * 32];
            const float4 f1 = *(const float4*)&p[s * 32 + 4];
            half8 h;
            h[0] = (_Float16)f0.x; h[1] = (_Float16)f0.y;
            h[2] = (_Float16)f0.z; h[3] = (_Float16)f0.w;
            h[4] = (_Float16)f1.x; h[5] = (_Float16)f1.y;
            h[6] = (_Float16)f1.z; h[7] = (_Float16)f1.w;
            a[s] = h;
        }
    } else {
        const _Float16* p = Ah + rowA * DD + q * 8;
#pragma unroll
        for (int s = 0; s < 4; s++) a[s] = *(const half8*)&p[s * 32];
    }
}

__global__ __launch_bounds__(256, 2) void gemm16(
    const _Float16* __restrict__ Ah,
    const float* __restrict__ Af32,
    const _Float16* __restrict__ WTh, const _Float16* __restrict__ WTl,
    const float* __restrict__ bias,
    const _Float16* __restrict__ Rh,
    _Float16* __restrict__ Oh,
    float* __restrict__ Of)
{
    const int lane = threadIdx.x & 63;
    const int ln   = lane & 15;
    const int q    = lane >> 4;
    const int wave0 = ((int)blockIdx.x * 256 + (int)threadIdx.x) >> 6;
    const int nWaves = ((int)gridDim.x * 256) >> 6;   // even => fixed col parity
    const int colBase = (wave0 & 1) * 64;

    // B-frag: lane holds B[k = s*32 + q*8 + j][n = colBase + b*16 + ln]
    half8 WH[4][4], WL[4][4];
#pragma unroll
    for (int s = 0; s < 4; s++) {
#pragma unroll
        for (int b = 0; b < 4; b++) {
            const size_t off = (size_t)(colBase + b * 16 + ln) * DD + s * 32 + q * 8;
            WH[s][b] = *(const half8*)&WTh[off];
            WL[s][b] = *(const half8*)&WTl[off];
        }
    }

    float biasv[4];
#pragma unroll
    for (int b = 0; b < 4; b++) biasv[b] = bias[colBase + b * 16 + ln];

    int task = wave0;
    half8 aCur[4], aNxt[4];
    if (task < NTASK)
        loadA(Ah, Af32, (size_t)(task >> 1) * 16 + ln, q, aCur);

    while (task < NTASK) {
        const int nt = task + nWaves;
        if (nt < NTASK)
            loadA(Ah, Af32, (size_t)(nt >> 1) * 16 + ln, q, aNxt);

        f32x4 acc[4];
#pragma unroll
        for (int b = 0; b < 4; b++)
            acc[b] = (f32x4){biasv[b], biasv[b], biasv[b], biasv[b]};

#pragma unroll
        for (int s = 0; s < 4; s++) {
#pragma unroll
            for (int b = 0; b < 4; b++) {
                acc[b] = __builtin_amdgcn_mfma_f32_16x16x32_f16(aCur[s], WH[s][b], acc[b], 0, 0, 0);
                acc[b] = __builtin_amdgcn_mfma_f32_16x16x32_f16(aCur[s], WL[s][b], acc[b], 0, 0, 0);
            }
        }

        // epilogue: C/D layout col = ln, row = q*4 + r
        const int tile = task >> 1;
#pragma unroll
        for (int b = 0; b < 4; b++) {
            const int col = colBase + b * 16 + ln;
#pragma unroll
            for (int r = 0; r < 4; r++) {
                const size_t row = (size_t)tile * 16 + q * 4 + r;
                float v = fmaxf(acc[b][r], 0.f);
                if (Rh) v += (float)Rh[row * DD + col];
                Oh[row * DD + col] = (_Float16)v;
                if (Of) Of[row * DD + col] = v;
            }
        }

        task = nt;
#pragma unroll
        for (int s = 0; s < 4; s++) aCur[s] = aNxt[s];
    }
}

// ---------------------------------------------------------------------------
// agg[n][:] = sum over csr[offs[n] .. +cnt[n]] of msg[s][:]
// 16 lanes/node, half8 (16B)/lane; fp32 accumulate, fp16 store.
// ---------------------------------------------------------------------------
__global__ __launch_bounds__(256) void aggregate16(
    const _Float16* __restrict__ msg,
    const int* __restrict__ offs, const int* __restrict__ cnt,
    const int* __restrict__ csr,
    _Float16* __restrict__ agg)
{
    const long long t = (long long)blockIdx.x * 256 + threadIdx.x;
    const int node = (int)(t >> 4);
    if (node >= NN) return;
    const int c8 = (int)(t & 15) * 8;

    const int base = offs[node];
    const int n = cnt[node];
    const int* bk = csr + base;

    float a0[8] = {0, 0, 0, 0, 0, 0, 0, 0};
    float a1[8] = {0, 0, 0, 0, 0, 0, 0, 0};
    int j = 0;
    for (; j + 1 < n; j += 2) {
        const half8 v0 = *(const half8*)&msg[(size_t)bk[j] * DD + c8];
        const half8 v1 = *(const half8*)&msg[(size_t)bk[j + 1] * DD + c8];
#pragma unroll
        for (int i = 0; i < 8; i++) { a0[i] += (float)v0[i]; a1[i] += (float)v1[i]; }
    }
    if (j < n) {
        const half8 v0 = *(const half8*)&msg[(size_t)bk[j] * DD + c8];
#pragma unroll
        for (int i = 0; i < 8; i++) a0[i] += (float)v0[i];
    }
    half8 o;
#pragma unroll
    for (int i = 0; i < 8; i++) o[i] = (_Float16)(a0[i] + a1[i]);
    *(half8*)&agg[(size_t)node * DD + c8] = o;
}

extern "C" void kernel_launch(void* const* d_in, const int* in_sizes, int n_in,
                              void* d_out, int out_size, void* d_ws, size_t ws_size,
                              hipStream_t stream) {
    const float* x  = (const float*)d_in[0];
    const int*   ei = (const int*)d_in[1];
    const float* Wi = (const float*)d_in[2];
    const float* bi = (const float*)d_in[3];
    const float* Wm = (const float*)d_in[4];
    const float* bm = (const float*)d_in[5];
    const float* Wu = (const float*)d_in[6];
    const float* bu = (const float*)d_in[7];

    const int* src = ei;           // edge_index[0] : gather source
    const int* dst = ei + NE;      // edge_index[1] : aggregation target

    // Workspace carve (~81 MB):
    const size_t NELE = (size_t)NN * DD;
    _Float16* msg = (_Float16*)d_ws;                     // 25.6 MB
    _Float16* agg = msg + NELE;                          // 25.6 MB
    _Float16* Sh  = agg + NELE;                          // 25.6 MB
    _Float16* WTh = Sh + NELE;                           // 288 KB
    _Float16* WTl = WTh + 9 * DD * DD;                   // 288 KB
    int* cnt  = (int*)(WTl + 9 * DD * DD);               // 400 KB  } contiguous,
    int* run  = cnt + NN;                                // 400 KB  } one memset
    int* offs = run + NN;                                // 400 KB
    int* bsum = offs + NN;                               // 1.6 KB
    int* boff = bsum + NB;                               // 1.6 KB
    int* csr  = boff + NB;                               // 2.56 MB

    // ---- CSR build (exact, L2-resident) ----
    hipMemsetAsync(cnt, 0, (size_t)2 * NN * 4, stream);  // cnt + run
    hist_k<<<1024, 256, 0, stream>>>(dst, cnt);
    bsum_k<<<NB, 256, 0, stream>>>(cnt, bsum);
    bscan_k<<<1, 512, 0, stream>>>(bsum, boff);
    offs_k<<<NB, 256, 0, stream>>>(cnt, boff, offs);
    scatter_k<<<1024, 256, 0, stream>>>(src, dst, offs, run, csr);

    wprep_k<<<9 * 128, 128, 0, stream>>>(Wi, Wm, Wu, WTh, WTl);

    const int GG = 512;     // 2048 waves; 2 blocks/CU resident
    const int AG = NTILE;   // 6250 blocks, 16 lanes/node

    // state = relu(x @ Wi + bi)   (fp32 A converted in-reg)
    gemm16<<<GG, 256, 0, stream>>>(nullptr, x, WTh, WTl, bi,
                                   nullptr, Sh, nullptr);

    for (int r = 0; r < ROUNDS; r++) {
        const _Float16* WmTh = WTh + (size_t)(1 + r) * DD * DD;
        const _Float16* WmTl = WTl + (size_t)(1 + r) * DD * DD;
        const _Float16* WuTh = WTh + (size_t)(5 + r) * DD * DD;
        const _Float16* WuTl = WTl + (size_t)(5 + r) * DD * DD;

        // msg = relu(state @ Wm[r] + bm[r])
        gemm16<<<GG, 256, 0, stream>>>(Sh, nullptr, WmTh, WmTl,
                                       bm + (size_t)r * DD,
                                       nullptr, msg, nullptr);
        // agg = segment_sum(msg[src], dst)
        aggregate16<<<AG, 256, 0, stream>>>(msg, offs, cnt, csr, agg);
        // state += relu(agg @ Wu[r] + bu[r]); final round also writes fp32 out
        gemm16<<<GG, 256, 0, stream>>>(agg, nullptr, WuTh, WuTl,
                                       bu + (size_t)r * DD,
                                       Sh, Sh,
                                       (r == ROUNDS - 1) ? (float*)d_out : nullptr);
    }
}